// Round 8
// baseline (369.058 us; speedup 1.0000x reference)
//
#include <hip/hip_runtime.h>
#include <math.h>

// ---------------------------------------------------------------------------
// MS-SSIM 3D (window 11, sigma 1.5, 5 levels) for (2,1,192,192,192) fp32 pairs.
//
// ws float layout:
//   [0..4]   ssim_sum[level]      (float atomics)
//   [5..9]   cs_sum[level]        (float atomics)
//   [10..14] min_enc[level]       (sortable-uint atomicMin)
//   [15..19] max_enc[level]       (sortable-uint atomicMax)
//   [20]     ssim completion counter (uint)
//   [21]     pyramid completion counter (uint)
//   [32.. ]  pyramid images (levels 1..4, img1 then img2 per level)
//
// R13: kill the pyramid->ssim serialization. The total-minus-ssim gap has
// been constant ~140 us across 7 rounds. Structure:
//   1. minmax_kernel (~10 us): L0 img1 min/max up front -> L0-ssim blocks
//      (576/760) have NO pyramid dependency.
//   2. fused_kernel: [864 pyramid | 760 ssim] in one dispatch. Pyramid
//      blocks signal ws[21] (threadfence release); only L1-4 ssim blocks
//      (184) spin on it (acquire). Deadlock-free by capacity: 184 spinners
//      < 1024 resident slots (40320B LDS union -> 4 blocks/CU), so
//      productive blocks always run regardless of dispatch order.
// ssim path is bit-exact R10 (159.7us proven); pyramid keeps R12
// vectorization, drops redundant L0 minmax. Min/max reorder-invariant.
// ---------------------------------------------------------------------------

typedef float f2 __attribute__((ext_vector_type(2)));
#define PKFMA(a, b, c) __builtin_elementwise_fma((a), (b), (c))

__device__ __forceinline__ f2 mkf2(float x, float y) { f2 r; r.x = x; r.y = y; return r; }

__device__ __forceinline__ unsigned enc_f(float f) {
    unsigned u = __float_as_uint(f);
    return (u & 0x80000000u) ? ~u : (u | 0x80000000u);
}
__device__ __forceinline__ float dec_f(unsigned e) {
    unsigned u = (e & 0x80000000u) ? (e ^ 0x80000000u) : ~e;
    return __uint_as_float(u);
}

__global__ void init_kernel(float* wsf) {
    unsigned* wsu = (unsigned*)wsf;
    int t = threadIdx.x;
    if (t < 10)       wsf[t] = 0.0f;
    else if (t < 15)  wsu[t] = 0xFFFFFFFFu;  // min slots
    else if (t < 22)  wsu[t] = 0u;           // max slots + both counters
}

// ---------------------------------------------------------------------------
// L0 min/max of img1 (both batch entries): 56.6 MB grid-stride float4 read.
// Removes the L0-ssim -> pyramid dependency.
// ---------------------------------------------------------------------------
__global__ void minmax_kernel(const float* img1, float* wsf) {
    unsigned* wsu = (unsigned*)wsf;
    __shared__ float smn[4], smx[4];
    const long N4 = 2L * 192 * 192 * 192 / 4;   // 3,538,944 float4
    const float4* p = (const float4*)img1;
    float mn = INFINITY, mx = -INFINITY;
    for (long i = (long)blockIdx.x * 256 + threadIdx.x; i < N4;
         i += (long)gridDim.x * 256) {
        float4 v = p[i];
        mn = fminf(mn, fminf(fminf(v.x, v.y), fminf(v.z, v.w)));
        mx = fmaxf(mx, fmaxf(fmaxf(v.x, v.y), fmaxf(v.z, v.w)));
    }
    for (int o = 32; o; o >>= 1) {
        mn = fminf(mn, __shfl_down(mn, o));
        mx = fmaxf(mx, __shfl_down(mx, o));
    }
    const int lane = threadIdx.x & 63, w = threadIdx.x >> 6;
    if (lane == 0) { smn[w] = mn; smx[w] = mx; }
    __syncthreads();
    if (threadIdx.x == 0) {
        for (int i = 1; i < 4; i++) { mn = fminf(mn, smn[i]); mx = fmaxf(mx, smx[i]); }
        atomicMin(&wsu[10], enc_f(mn));
        atomicMax(&wsu[15], enc_f(mx));
    }
}

// ---------------------------------------------------------------------------
// Fused pyramid + ssim kernel.
// ---------------------------------------------------------------------------
#define TSX 16
#define TSY 32
#define EXR 42            // ext rows (32+10)
#define EXC 26            // ext cols (16+10)
#define SPS 26            // S row stride in float2 (exact 13 float4, odd)
#define NPIX (EXR * EXC)  // 1092
#define TPS 17            // TX row stride in float4
#define NPYR (216 * 2 * 2)

struct FusedParams {
    const float* A[5];
    const float* B[5];
    float* out;
    double cnt[5];
    int D[5], O[5], zc[5], nTx[5], nTy[5];
    int blk0[6];          // cumulative ssim block offsets, level order 0..4
    float g[11];          // gaussian taps (uniform -> SGPRs)
    const float* psrc[2]; // pyramid inputs (img1, img2)
    float* pdst[2][4];    // pyramid outputs [img][level-1]
};

// No waves_per_eu attr (R6 lesson: forcing occupancy spills Acc to scratch).
__launch_bounds__(256)
__global__ void fused_kernel(FusedParams P, float* wsf) {
    // LDS union: pyramid path needs 18,976 B; ssim path needs 40,320 B.
    __shared__ __align__(16) char Ubuf[40320];
    unsigned* wsu = (unsigned*)wsf;
    const int tid = threadIdx.x;

    if (blockIdx.x < NPYR) {
        // ================= pyramid path =================
        float* L1  = (float*)Ubuf;     // 4096 floats (16^3)
        float* L2  = L1 + 4096;        // 512 (8^3)
        float* L3  = L2 + 512;         // 64 (4^3)
        float* smn = L3 + 64;          // 4
        float* smx = smn + 4;          // 4

        int blk = blockIdx.x;
        int r = blk % 216; blk /= 216;
        int batch = blk & 1;
        int im = blk >> 1;
        const int rx = r % 6, ry = (r / 6) % 6, rz = r / 36;

        const long N0 = 192L * 192 * 192;
        const float* src = P.psrc[im] + (long)batch * N0;
        float* d1 = P.pdst[im][0] + (long)batch * 96 * 96 * 96;
        float* d2 = P.pdst[im][1] + (long)batch * 48 * 48 * 48;
        float* d3 = P.pdst[im][2] + (long)batch * 24 * 24 * 24;
        float* d4 = P.pdst[im][3] + (long)batch * 12 * 12 * 12;

        float mnv[5], mxv[5];
#pragma unroll
        for (int l = 1; l < 5; l++) { mnv[l] = INFINITY; mxv[l] = -INFINITY; }

        // stage 1: 32^3 -> 16^3 vectorized (R12). L0 minmax handled by
        // minmax_kernel now -- dropped here.
        {
            const int tx2 = tid & 7;
            const int ty  = (tid >> 3) & 15;
            const int zh  = tid >> 7;
            const long D = 192, D2 = 192L * 192;
            const int gx = 2 * (rx * 16) + 4 * tx2;
            const int gy = 2 * (ry * 16 + ty);
#pragma unroll 2
            for (int it = 0; it < 8; it++) {
                const int zo = 2 * it + zh;
                const int gz = 2 * (rz * 16 + zo);
                long base = (long)gz * D2 + (long)gy * D + gx;
                float4 a00 = *(const float4*)(src + base);
                float4 a01 = *(const float4*)(src + base + D);
                float4 a10 = *(const float4*)(src + base + D2);
                float4 a11 = *(const float4*)(src + base + D2 + D);
                float s0 = (a00.x + a00.y + a01.x + a01.y +
                            a10.x + a10.y + a11.x + a11.y) * 0.125f;
                float s1 = (a00.z + a00.w + a01.z + a01.w +
                            a10.z + a10.w + a11.z + a11.w) * 0.125f;
                mnv[1] = fminf(mnv[1], fminf(s0, s1));
                mxv[1] = fmaxf(mxv[1], fmaxf(s0, s1));
                *(float2*)&d1[(long)(rz * 16 + zo) * 96 * 96 +
                              (ry * 16 + ty) * 96 + (rx * 16 + 2 * tx2)] =
                    make_float2(s0, s1);
                *(float2*)&L1[zo * 256 + ty * 16 + 2 * tx2] = make_float2(s0, s1);
            }
        }
        __syncthreads();

#pragma unroll
        for (int k = 0; k < 2; k++) {
            int o = tid + (k << 8);
            int x = o & 7, y = (o >> 3) & 7, z = o >> 6;
            float s = (L1[(2 * z) * 256 + (2 * y) * 16 + 2 * x] +
                       L1[(2 * z) * 256 + (2 * y) * 16 + 2 * x + 1] +
                       L1[(2 * z) * 256 + (2 * y + 1) * 16 + 2 * x] +
                       L1[(2 * z) * 256 + (2 * y + 1) * 16 + 2 * x + 1] +
                       L1[(2 * z + 1) * 256 + (2 * y) * 16 + 2 * x] +
                       L1[(2 * z + 1) * 256 + (2 * y) * 16 + 2 * x + 1] +
                       L1[(2 * z + 1) * 256 + (2 * y + 1) * 16 + 2 * x] +
                       L1[(2 * z + 1) * 256 + (2 * y + 1) * 16 + 2 * x + 1]) * 0.125f;
            mnv[2] = fminf(mnv[2], s); mxv[2] = fmaxf(mxv[2], s);
            d2[(long)(rz * 8 + z) * 48 * 48 + (ry * 8 + y) * 48 + (rx * 8 + x)] = s;
            L2[o] = s;
        }
        __syncthreads();

        if (tid < 64) {
            int x = tid & 3, y = (tid >> 2) & 3, z = tid >> 4;
            float s = (L2[(2 * z) * 64 + (2 * y) * 8 + 2 * x] +
                       L2[(2 * z) * 64 + (2 * y) * 8 + 2 * x + 1] +
                       L2[(2 * z) * 64 + (2 * y + 1) * 8 + 2 * x] +
                       L2[(2 * z) * 64 + (2 * y + 1) * 8 + 2 * x + 1] +
                       L2[(2 * z + 1) * 64 + (2 * y) * 8 + 2 * x] +
                       L2[(2 * z + 1) * 64 + (2 * y) * 8 + 2 * x + 1] +
                       L2[(2 * z + 1) * 64 + (2 * y + 1) * 8 + 2 * x] +
                       L2[(2 * z + 1) * 64 + (2 * y + 1) * 8 + 2 * x + 1]) * 0.125f;
            mnv[3] = fminf(mnv[3], s); mxv[3] = fmaxf(mxv[3], s);
            d3[(long)(rz * 4 + z) * 24 * 24 + (ry * 4 + y) * 24 + (rx * 4 + x)] = s;
            L3[tid] = s;
        }
        __syncthreads();

        if (tid < 8) {
            int x = tid & 1, y = (tid >> 1) & 1, z = tid >> 2;
            float s = (L3[(2 * z) * 16 + (2 * y) * 4 + 2 * x] +
                       L3[(2 * z) * 16 + (2 * y) * 4 + 2 * x + 1] +
                       L3[(2 * z) * 16 + (2 * y + 1) * 4 + 2 * x] +
                       L3[(2 * z) * 16 + (2 * y + 1) * 4 + 2 * x + 1] +
                       L3[(2 * z + 1) * 16 + (2 * y) * 4 + 2 * x] +
                       L3[(2 * z + 1) * 16 + (2 * y) * 4 + 2 * x + 1] +
                       L3[(2 * z + 1) * 16 + (2 * y + 1) * 4 + 2 * x] +
                       L3[(2 * z + 1) * 16 + (2 * y + 1) * 4 + 2 * x + 1]) * 0.125f;
            mnv[4] = fminf(mnv[4], s); mxv[4] = fmaxf(mxv[4], s);
            d4[(long)(rz * 2 + z) * 12 * 12 + (ry * 2 + y) * 12 + (rx * 2 + x)] = s;
        }

        const int lane = tid & 63, w = tid >> 6;
#pragma unroll
        for (int l = 1; l < 5; l++) {
            float mn = mnv[l], mx = mxv[l];
            for (int o = 32; o; o >>= 1) {
                mn = fminf(mn, __shfl_down(mn, o));
                mx = fmaxf(mx, __shfl_down(mx, o));
            }
            __syncthreads();
            if (lane == 0) { smn[w] = mn; smx[w] = mx; }
            __syncthreads();
            if (tid == 0 && im == 0) {
                for (int i = 1; i < 4; i++) { mn = fminf(mn, smn[i]); mx = fmaxf(mx, smx[i]); }
                atomicMin(&wsu[10 + l], enc_f(mn));
                atomicMax(&wsu[15 + l], enc_f(mx));
            }
        }

        // release: all block stores drained by the barrier above; flush L2,
        // then bump the pyramid-complete counter (device-scope RMW).
        __syncthreads();
        if (tid == 0) { __threadfence(); atomicAdd(&wsu[21], 1u); }
        return;
    }

    // ================= ssim path (bit-exact R10) =================
    float2* S0 = (float2*)Ubuf;            // EXR*SPS float2
    float2* S1 = S0 + EXR * SPS;
    float4* T0 = (float4*)(S1 + EXR * SPS);
    float4* T1 = T0 + EXR * TPS;

    const int col = tid & 15;
    const int yg  = tid >> 4;      // 0..15, owns output rows 2yg, 2yg+1

    // ---- decode level + tile from ssim-relative block index
    int level = 0;
    {
        int b = blockIdx.x - NPYR;
#pragma unroll
        for (int l = 1; l < 5; l++)
            if (b >= P.blk0[l]) level = l;
    }
    int rel = (blockIdx.x - NPYR) - P.blk0[level];

    // L1-4 blocks need pyramid data + per-level minmax: acquire-wait on
    // the pyramid counter. <=184 spinners << 1024 resident capacity ->
    // deadlock-free for any dispatch order. L0 blocks proceed immediately
    // (minmax_kernel completed before this dispatch).
    if (level > 0) {
        if (tid == 0) {
            while (atomicAdd(&wsu[21], 0u) < NPYR) __builtin_amdgcn_s_sleep(8);
            __threadfence();   // acquire: invalidate stale cache lines
        }
        __syncthreads();
    }

    const int D   = P.D[level];
    const int O   = P.O[level];
    const int ZC  = P.zc[level];
    const int nTx = P.nTx[level];
    const int nTy = P.nTy[level];

    const int tx = rel % nTx;  rel /= nTx;
    const int ty = rel % nTy;  rel /= nTy;
    const int batch = rel & 1;
    const int chunk = rel >> 1;

    const int oz0 = chunk * ZC;
    const int oz1 = min(oz0 + ZC, O);
    const int nplanes = oz1 - oz0 + 10;
    const int ox0 = tx * TSX;
    const int oy0 = ty * TSY;
    const int D2  = D * D;
    const float* A = P.A[level] + (long)batch * D * D2;
    const float* B = P.B[level] + (long)batch * D * D2;

    // C1/C2 from this level's img1 min/max
    float mxv = dec_f(wsu[15 + level]);
    float mnv = dec_f(wsu[10 + level]);
    float maxval = (mxv > 128.f) ? 255.f : 1.f;
    float minval = (mnv < -0.5f) ? -1.f : 0.f;
    float Lr = maxval - minval;
    float C1 = 0.01f * Lr; C1 *= C1;
    float C2 = 0.03f * Lr; C2 *= C2;

    // per-thread staging slots (plane-invariant offsets); 1092 = 42*26
    int  poff[5], sidx[5];
    bool pval[5];
#pragma unroll
    for (int k = 0; k < 5; k++) {
        int idx = tid + (k << 8);
        pval[k] = (idx < NPIX);
        int row = idx / EXC;
        int c   = idx - row * EXC;
        sidx[k] = row * SPS + c;
        int gy = min(oy0 + row, D - 1);
        int gx = min(ox0 + c,   D - 1);
        poff[k] = gy * D + gx;
    }

    // packed systolic z accumulators: Acc2[field][k] = (even-row, odd-row)
    // fields: 0=m1, 1=m2, 2=sq(a^2+b^2), 3=sab
    f2 Acc2[4][11] = {};
    float ssim_acc = 0.f, cs_acc = 0.f;

    const bool vx  = (ox0 + col < O);
    const bool vy0 = vx && (oy0 + 2 * yg < O);
    const bool vy1 = vx && (oy0 + 2 * yg + 1 < O);

    // preload first plane
    float2 Pld[5];
    {
        long zoff = (long)oz0 * D2;
#pragma unroll
        for (int k = 0; k < 5; k++)
            if (pval[k]) Pld[k] = make_float2(A[zoff + poff[k]], B[zoff + poff[k]]);
    }

    // Pipeline: iter it: stage S(it) | x-conv plane it-1 | y-conv plane it-2.
    for (int it = 0; it < nplanes + 2; ++it) {
        // ---- A: stage plane `it` into S[it&1]; prefetch plane it+1
        if (it < nplanes) {
            float2* Sc = (it & 1) ? S1 : S0;
#pragma unroll
            for (int k = 0; k < 5; k++)
                if (pval[k]) Sc[sidx[k]] = Pld[k];
            if (it + 1 < nplanes) {
                long zoff = (long)(oz0 + it + 1) * D2;
#pragma unroll
                for (int k = 0; k < 5; k++)
                    if (pval[k]) Pld[k] = make_float2(A[zoff + poff[k]], B[zoff + poff[k]]);
            }
        }

        // ---- B: x-conv plane it-1: S[(it-1)&1] -> TX[(it-1)&1]
        if (it >= 1 && it <= nplanes && tid < EXR * 4) {
            const float2* Sc = ((it - 1) & 1) ? S1 : S0;
            float4* Tc = ((it - 1) & 1) ? T1 : T0;
            const int row = tid >> 2;
            const int cg  = tid & 3;          // c0 = 4*cg
            const float4* srow = (const float4*)(Sc + row * SPS);
            f2 mm[4] = {}, qq[4] = {};
#pragma unroll
            for (int i = 0; i < 7; i++) {
                float4 qv = srow[2 * cg + i];
#pragma unroll
                for (int h = 0; h < 2; h++) {
                    const int jj = 2 * i + h;
                    float a = h ? qv.z : qv.x;
                    float b = h ? qv.w : qv.y;
                    f2 ab  = mkf2(a, b);
                    float e  = a * b;
                    float s2 = fmaf(a, a, b * b);
                    f2 se2 = mkf2(s2, e);
#pragma unroll
                    for (int cc = 0; cc < 4; cc++) {
                        const int j = jj - cc;
                        if (j >= 0 && j <= 10) {
                            f2 w = mkf2(P.g[j], P.g[j]);
                            mm[cc] = PKFMA(w, ab,  mm[cc]);
                            qq[cc] = PKFMA(w, se2, qq[cc]);
                        }
                    }
                }
            }
#pragma unroll
            for (int cc = 0; cc < 4; cc++)
                Tc[row * TPS + 4 * cg + cc] =
                    make_float4(mm[cc].x, mm[cc].y, qq[cc].x, qq[cc].y);
        }

        // ---- C: y-conv + systolic for plane it-2 (reads TX[(it-2)&1 == it&1])
        if (it >= 2) {
            const float4* Tc = (it & 1) ? T1 : T0;
            f2 acc[4] = {};
#pragma unroll
            for (int j = 0; j < 12; j++) {
                float4 q = Tc[(2 * yg + j) * TPS + col];
                float we = (j < 11) ? P.g[j]     : 0.f;
                float wo = (j > 0)  ? P.g[j - 1] : 0.f;
                f2 w = mkf2(we, wo);
                acc[0] = PKFMA(w, mkf2(q.x, q.x), acc[0]);
                acc[1] = PKFMA(w, mkf2(q.y, q.y), acc[1]);
                acc[2] = PKFMA(w, mkf2(q.z, q.z), acc[2]);
                acc[3] = PKFMA(w, mkf2(q.w, q.w), acc[3]);
            }

            // packed systolic z-accumulate: A[k] = g[10-k]*s + A[k+1]
#pragma unroll
            for (int f = 0; f < 4; f++) {
                f2 s = acc[f];
#pragma unroll
                for (int k = 0; k < 10; k++) {
                    f2 w = mkf2(P.g[10 - k], P.g[10 - k]);
                    Acc2[f][k] = PKFMA(w, s, Acc2[f][k + 1]);
                }
                Acc2[f][10] = mkf2(P.g[0], P.g[0]) * s;
            }

            // completed output plane: Acc2[..][0] holds plane (it-2)-10 conv
            if (it >= 12) {
#pragma unroll
                for (int r = 0; r < 2; r++) {
                    bool valid = r ? vy1 : vy0;
                    if (!valid) continue;
                    float m1v = r ? Acc2[0][0].y : Acc2[0][0].x;
                    float m2v = r ? Acc2[1][0].y : Acc2[1][0].x;
                    float sqv = r ? Acc2[2][0].y : Acc2[2][0].x;
                    float sbv = r ? Acc2[3][0].y : Acc2[3][0].x;
                    float mu11 = m1v * m1v, mu22 = m2v * m2v, mu12 = m1v * m2v;
                    float sg12 = sbv - mu12;
                    float sgs  = sqv - mu11 - mu22;     // sigma1_sq + sigma2_sq
                    float v1 = 2.f * sg12 + C2;
                    float v2 = sgs + C2;
                    cs_acc   += v1 / v2;
                    ssim_acc += ((2.f * mu12 + C1) * v1) / ((mu11 + mu22 + C1) * v2);
                }
            }
        }

        __syncthreads();
    }

    // block reduce (reuse S's LDS; loop ended with a barrier so S is dead)
    float2* RED = (float2*)S0;
    RED[tid] = make_float2(ssim_acc, cs_acc);
    __syncthreads();
    for (int s = 128; s > 0; s >>= 1) {
        if (tid < s) {
            RED[tid].x += RED[tid + s].x;
            RED[tid].y += RED[tid + s].y;
        }
        __syncthreads();
    }
    if (tid == 0) {
        atomicAdd(&wsf[level],     RED[0].x);
        atomicAdd(&wsf[5 + level], RED[0].y);
        __threadfence();
        unsigned prev = atomicAdd(&wsu[20], 1u);
        if (prev == (unsigned)(P.blk0[5] - 1)) {
            // all ssim blocks' sums globally visible; read via device-scope
            // RMW to dodge stale L2.
            double w[5];
            w[0] = (double)0.0448f; w[1] = (double)0.2856f; w[2] = (double)0.3001f;
            w[3] = (double)0.2363f; w[4] = (double)0.1333f;
            double prod = 1.0;
            for (int l = 0; l < 4; l++) {
                float cs = atomicAdd(&wsf[5 + l], 0.0f);
                prod *= pow((double)cs / P.cnt[l], w[l]);
            }
            float sm = atomicAdd(&wsf[4], 0.0f);
            prod *= pow((double)sm / P.cnt[4], w[4]);
            P.out[0] = (float)prod;
        }
    }
}

extern "C" void kernel_launch(void* const* d_in, const int* in_sizes, int n_in,
                              void* d_out, int out_size, void* d_ws, size_t ws_size,
                              hipStream_t stream) {
    (void)in_sizes; (void)n_in; (void)out_size; (void)ws_size;
    const float* img1 = (const float*)d_in[0];
    const float* img2 = (const float*)d_in[1];
    float* wsf = (float*)d_ws;
    float* out = (float*)d_out;

    const int Ds[5]  = {192, 96, 48, 24, 12};
    // single-phase packing: 576 L0 + 144 L1 + 36 L2 + 2 L3 + 2 L4 = 760
    const int ZCs[5] = {46, 26, 14, 14, 2};

    // pyramid buffers in workspace
    float* bufA[5] = {nullptr};
    float* bufB[5] = {nullptr};
    size_t o = 32;
    for (int l = 1; l < 5; l++) {
        long n = 2L * Ds[l] * Ds[l] * Ds[l];
        bufA[l] = wsf + o; o += (size_t)n;
        bufB[l] = wsf + o; o += (size_t)n;
    }

    init_kernel<<<1, 64, 0, stream>>>(wsf);
    minmax_kernel<<<1024, 256, 0, stream>>>(img1, wsf);

    FusedParams P;
    P.A[0] = img1; P.B[0] = img2;
    for (int l = 1; l < 5; l++) { P.A[l] = bufA[l]; P.B[l] = bufB[l]; }
    P.out = out;
    P.psrc[0] = img1; P.psrc[1] = img2;
    for (int l = 1; l < 5; l++) { P.pdst[0][l - 1] = bufA[l]; P.pdst[1][l - 1] = bufB[l]; }
    int acc = 0;
    for (int l = 0; l < 5; l++) {
        int D = Ds[l], O = D - 10, ZC = ZCs[l];
        int nTx = (O + TSX - 1) / TSX;
        int nTy = (O + TSY - 1) / TSY;
        int ZCn = (O + ZC - 1) / ZC;
        P.D[l] = D; P.O[l] = O; P.zc[l] = ZC; P.nTx[l] = nTx; P.nTy[l] = nTy;
        P.blk0[l] = acc;
        acc += nTx * nTy * 2 * ZCn;
        double Od = (double)O;
        P.cnt[l] = 2.0 * Od * Od * Od;
    }
    P.blk0[5] = acc;

    // gaussian taps (same float expression the original device version used)
    {
        float s = 0.f;
        for (int i = 0; i < 11; i++) {
            float d = (float)(i - 5);
            P.g[i] = expf(-d * d / 4.5f);
            s += P.g[i];
        }
        for (int i = 0; i < 11; i++) P.g[i] /= s;
    }

    fused_kernel<<<NPYR + acc, 256, 0, stream>>>(P, wsf);
}

// Round 10
// 336.198 us; speedup vs baseline: 1.0977x; 1.0977x over previous
//
#include <hip/hip_runtime.h>
#include <math.h>

// ---------------------------------------------------------------------------
// MS-SSIM 3D (window 11, sigma 1.5, 5 levels) for (2,1,192,192,192) fp32 pairs.
//
// ws float layout:
//   [0..4]   ssim_sum[level]      (float atomics)
//   [5..9]   cs_sum[level]        (float atomics)
//   [10..14] min_enc[level]       (sortable-uint atomicMin)
//   [15..19] max_enc[level]       (sortable-uint atomicMax)
//   [20]     completion counter   (uint)
//   [32.. ]  pyramid images (levels 1..4, img1 then img2 per level)
//
// R14 (resubmit; round 9 was a container-infra failure, no kernel signal):
// occupancy via LDS cut. R13 proved the ~100us residual is fixed harness
// overhead (fusion didn't shrink it) -- serial 3-dispatch skeleton. ssim is
// latency-bound (VALU 48%, HBM 16%, ~3 blocks/CU, grid-limited residency).
// Single TX buffer via loop reorder C(y-conv, reads TX) -> A(stage S) ->
// bar -> B(x-conv, writes TX) -> bar (2 barriers/plane, proven ~neutral in
// R7): LDS 40320 -> 28896 B = 5 blocks/CU capacity. Grid ZCs{26,26,14,14,2}
// = 1192 blocks (~4.66/CU, single-phase, uniform durations). +12% staging
// for +55% waves. ssim math/packing bit-exact R10 (159.7us proven).
// ---------------------------------------------------------------------------

typedef float f2 __attribute__((ext_vector_type(2)));
#define PKFMA(a, b, c) __builtin_elementwise_fma((a), (b), (c))

__device__ __forceinline__ f2 mkf2(float x, float y) { f2 r; r.x = x; r.y = y; return r; }

__device__ __forceinline__ unsigned enc_f(float f) {
    unsigned u = __float_as_uint(f);
    return (u & 0x80000000u) ? ~u : (u | 0x80000000u);
}
__device__ __forceinline__ float dec_f(unsigned e) {
    unsigned u = (e & 0x80000000u) ? (e ^ 0x80000000u) : ~e;
    return __uint_as_float(u);
}

__global__ void init_kernel(float* wsf) {
    unsigned* wsu = (unsigned*)wsf;
    int t = threadIdx.x;
    if (t < 10)       wsf[t] = 0.0f;
    else if (t < 15)  wsu[t] = 0xFFFFFFFFu;  // min slots
    else if (t < 20)  wsu[t] = 0u;           // max slots
    else if (t == 20) wsu[t] = 0u;           // completion counter
}

// ---------------------------------------------------------------------------
// Fused pyramid: each block owns a 32^3 region of level 0 for one (img,batch),
// produces 16^3 of L1, 8^3 of L2, 4^3 of L3, 2^3 of L4 via LDS, writes all
// levels to global, and block-reduces min/max per level (img1 only).
// R12 vectorization: float4 loads, 2 outputs/thread/iter.
// ---------------------------------------------------------------------------
struct PyrParams {
    const float* src[2];   // img1, img2
    float* dst[2][4];      // [img][level-1]
};

__launch_bounds__(256, 4)
__global__ void pyramid_kernel(PyrParams P, float* wsf) {
    __shared__ float L1[16 * 256];   // 16^3
    __shared__ float L2[512];        // 8^3
    __shared__ float L3[64];         // 4^3
    __shared__ float smn[4], smx[4];
    unsigned* wsu = (unsigned*)wsf;

    const int tid = threadIdx.x;
    int blk = blockIdx.x;
    int r = blk % 216; blk /= 216;
    int batch = blk & 1;
    int im = blk >> 1;
    const int rx = r % 6, ry = (r / 6) % 6, rz = r / 36;

    const long N0 = 192L * 192 * 192;
    const float* src = P.src[im] + (long)batch * N0;
    float* d1 = P.dst[im][0] + (long)batch * 96 * 96 * 96;
    float* d2 = P.dst[im][1] + (long)batch * 48 * 48 * 48;
    float* d3 = P.dst[im][2] + (long)batch * 24 * 24 * 24;
    float* d4 = P.dst[im][3] + (long)batch * 12 * 12 * 12;

    float mnv[5], mxv[5];
#pragma unroll
    for (int l = 0; l < 5; l++) { mnv[l] = INFINITY; mxv[l] = -INFINITY; }

    // ---- stage 1: 32^3 -> 16^3, vectorized (R12).
    {
        const int tx2 = tid & 7;
        const int ty  = (tid >> 3) & 15;
        const int zh  = tid >> 7;
        const long D = 192, D2 = 192L * 192;
        const int gx = 2 * (rx * 16) + 4 * tx2;
        const int gy = 2 * (ry * 16 + ty);
#pragma unroll 2
        for (int it = 0; it < 8; it++) {
            const int zo = 2 * it + zh;
            const int gz = 2 * (rz * 16 + zo);
            long base = (long)gz * D2 + (long)gy * D + gx;
            float4 a00 = *(const float4*)(src + base);
            float4 a01 = *(const float4*)(src + base + D);
            float4 a10 = *(const float4*)(src + base + D2);
            float4 a11 = *(const float4*)(src + base + D2 + D);
            float lo = fminf(fminf(fminf(fminf(a00.x, a00.y), fminf(a00.z, a00.w)),
                                   fminf(fminf(a01.x, a01.y), fminf(a01.z, a01.w))),
                             fminf(fminf(fminf(a10.x, a10.y), fminf(a10.z, a10.w)),
                                   fminf(fminf(a11.x, a11.y), fminf(a11.z, a11.w))));
            float hi = fmaxf(fmaxf(fmaxf(fmaxf(a00.x, a00.y), fmaxf(a00.z, a00.w)),
                                   fmaxf(fmaxf(a01.x, a01.y), fmaxf(a01.z, a01.w))),
                             fmaxf(fmaxf(fmaxf(a10.x, a10.y), fmaxf(a10.z, a10.w)),
                                   fmaxf(fmaxf(a11.x, a11.y), fmaxf(a11.z, a11.w))));
            mnv[0] = fminf(mnv[0], lo); mxv[0] = fmaxf(mxv[0], hi);
            float s0 = (a00.x + a00.y + a01.x + a01.y +
                        a10.x + a10.y + a11.x + a11.y) * 0.125f;
            float s1 = (a00.z + a00.w + a01.z + a01.w +
                        a10.z + a10.w + a11.z + a11.w) * 0.125f;
            mnv[1] = fminf(mnv[1], fminf(s0, s1));
            mxv[1] = fmaxf(mxv[1], fmaxf(s0, s1));
            *(float2*)&d1[(long)(rz * 16 + zo) * 96 * 96 +
                          (ry * 16 + ty) * 96 + (rx * 16 + 2 * tx2)] =
                make_float2(s0, s1);
            *(float2*)&L1[zo * 256 + ty * 16 + 2 * tx2] = make_float2(s0, s1);
        }
    }
    __syncthreads();

#pragma unroll
    for (int k = 0; k < 2; k++) {
        int o = tid + (k << 8);
        int x = o & 7, y = (o >> 3) & 7, z = o >> 6;
        float s = (L1[(2 * z) * 256 + (2 * y) * 16 + 2 * x] +
                   L1[(2 * z) * 256 + (2 * y) * 16 + 2 * x + 1] +
                   L1[(2 * z) * 256 + (2 * y + 1) * 16 + 2 * x] +
                   L1[(2 * z) * 256 + (2 * y + 1) * 16 + 2 * x + 1] +
                   L1[(2 * z + 1) * 256 + (2 * y) * 16 + 2 * x] +
                   L1[(2 * z + 1) * 256 + (2 * y) * 16 + 2 * x + 1] +
                   L1[(2 * z + 1) * 256 + (2 * y + 1) * 16 + 2 * x] +
                   L1[(2 * z + 1) * 256 + (2 * y + 1) * 16 + 2 * x + 1]) * 0.125f;
        mnv[2] = fminf(mnv[2], s); mxv[2] = fmaxf(mxv[2], s);
        d2[(long)(rz * 8 + z) * 48 * 48 + (ry * 8 + y) * 48 + (rx * 8 + x)] = s;
        L2[o] = s;
    }
    __syncthreads();

    if (tid < 64) {
        int x = tid & 3, y = (tid >> 2) & 3, z = tid >> 4;
        float s = (L2[(2 * z) * 64 + (2 * y) * 8 + 2 * x] +
                   L2[(2 * z) * 64 + (2 * y) * 8 + 2 * x + 1] +
                   L2[(2 * z) * 64 + (2 * y + 1) * 8 + 2 * x] +
                   L2[(2 * z) * 64 + (2 * y + 1) * 8 + 2 * x + 1] +
                   L2[(2 * z + 1) * 64 + (2 * y) * 8 + 2 * x] +
                   L2[(2 * z + 1) * 64 + (2 * y) * 8 + 2 * x + 1] +
                   L2[(2 * z + 1) * 64 + (2 * y + 1) * 8 + 2 * x] +
                   L2[(2 * z + 1) * 64 + (2 * y + 1) * 8 + 2 * x + 1]) * 0.125f;
        mnv[3] = fminf(mnv[3], s); mxv[3] = fmaxf(mxv[3], s);
        d3[(long)(rz * 4 + z) * 24 * 24 + (ry * 4 + y) * 24 + (rx * 4 + x)] = s;
        L3[tid] = s;
    }
    __syncthreads();

    if (tid < 8) {
        int x = tid & 1, y = (tid >> 1) & 1, z = tid >> 2;
        float s = (L3[(2 * z) * 16 + (2 * y) * 4 + 2 * x] +
                   L3[(2 * z) * 16 + (2 * y) * 4 + 2 * x + 1] +
                   L3[(2 * z) * 16 + (2 * y + 1) * 4 + 2 * x] +
                   L3[(2 * z) * 16 + (2 * y + 1) * 4 + 2 * x + 1] +
                   L3[(2 * z + 1) * 16 + (2 * y) * 4 + 2 * x] +
                   L3[(2 * z + 1) * 16 + (2 * y) * 4 + 2 * x + 1] +
                   L3[(2 * z + 1) * 16 + (2 * y + 1) * 4 + 2 * x] +
                   L3[(2 * z + 1) * 16 + (2 * y + 1) * 4 + 2 * x + 1]) * 0.125f;
        mnv[4] = fminf(mnv[4], s); mxv[4] = fmaxf(mxv[4], s);
        d4[(long)(rz * 2 + z) * 12 * 12 + (ry * 2 + y) * 12 + (rx * 2 + x)] = s;
    }

    const int lane = tid & 63, w = tid >> 6;
#pragma unroll
    for (int l = 0; l < 5; l++) {
        float mn = mnv[l], mx = mxv[l];
        for (int o = 32; o; o >>= 1) {
            mn = fminf(mn, __shfl_down(mn, o));
            mx = fmaxf(mx, __shfl_down(mx, o));
        }
        __syncthreads();
        if (lane == 0) { smn[w] = mn; smx[w] = mx; }
        __syncthreads();
        if (tid == 0 && im == 0) {
            for (int i = 1; i < 4; i++) { mn = fminf(mn, smn[i]); mx = fmaxf(mx, smx[i]); }
            atomicMin(&wsu[10 + l], enc_f(mn));
            atomicMax(&wsu[15 + l], enc_f(mx));
        }
    }
}

// ---------------------------------------------------------------------------
// Combined SSIM kernel: one dispatch, all 5 levels + fused final reduction.
// 16(x) x 32(y) output tile; thread owns (col, 2 rows). Per iter:
//   C: y-conv+systolic plane it-2 (reads TX, written last iter)
//   A: stage S(it) + prefetch it+1 (S double-buffered)
//   barrier  (TX consumed -> safe to overwrite)
//   B: x-conv plane it-1 -> TX (single buffer)
//   barrier  (TX ready for next C; S(it) visible for next B)
// Hot loops packed fp32 (v_pk_fma_f32 via float2 ext_vector fma), math
// bit-exact R10.
// ---------------------------------------------------------------------------
#define TSX 16
#define TSY 32
#define EXR 42            // ext rows (32+10)
#define EXC 26            // ext cols (16+10)
#define SPS 26            // S row stride in float2 (exact 13 float4, odd)
#define NPIX (EXR * EXC)  // 1092
#define TPS 17            // TX row stride in float4

struct AllParams {
    const float* A[5];
    const float* B[5];
    float* out;
    double cnt[5];
    int D[5], O[5], zc[5], nTx[5], nTy[5];
    int blk0[6];          // cumulative block offsets, level order 0..4
    float g[11];          // gaussian taps (uniform -> SGPRs)
};

// No waves_per_eu attr (R6 lesson: forcing occupancy spills Acc to scratch).
__launch_bounds__(256)
__global__ void ssim_all_kernel(AllParams P, float* wsf) {
    __shared__ __align__(16) float2 S[2][EXR * SPS];  // 2 x 8736 B
    __shared__ __align__(16) float4 TX4[EXR * TPS];   // 11424 B (single)
    // total 28,896 B -> 5 blocks/CU capacity

    const int tid = threadIdx.x;
    const int col = tid & 15;
    const int yg  = tid >> 4;      // 0..15, owns output rows 2yg, 2yg+1

    // ---- decode level + tile from flat blockIdx.x
    int level = 0;
    {
        int b = blockIdx.x;
#pragma unroll
        for (int l = 1; l < 5; l++)
            if (b >= P.blk0[l]) level = l;
    }
    int rel = blockIdx.x - P.blk0[level];
    const int D   = P.D[level];
    const int O   = P.O[level];
    const int ZC  = P.zc[level];
    const int nTx = P.nTx[level];
    const int nTy = P.nTy[level];

    const int tx = rel % nTx;  rel /= nTx;
    const int ty = rel % nTy;  rel /= nTy;
    const int batch = rel & 1;
    const int chunk = rel >> 1;

    const int oz0 = chunk * ZC;
    const int oz1 = min(oz0 + ZC, O);
    const int nplanes = oz1 - oz0 + 10;
    const int ox0 = tx * TSX;
    const int oy0 = ty * TSY;
    const int D2  = D * D;
    const float* A = P.A[level] + (long)batch * D * D2;
    const float* B = P.B[level] + (long)batch * D * D2;

    // C1/C2 from this level's img1 min/max (computed by pyramid kernel)
    const unsigned* wsu = (const unsigned*)wsf;
    float mxv = dec_f(wsu[15 + level]);
    float mnv = dec_f(wsu[10 + level]);
    float maxval = (mxv > 128.f) ? 255.f : 1.f;
    float minval = (mnv < -0.5f) ? -1.f : 0.f;
    float Lr = maxval - minval;
    float C1 = 0.01f * Lr; C1 *= C1;
    float C2 = 0.03f * Lr; C2 *= C2;

    // per-thread staging slots (plane-invariant offsets); 1092 = 42*26
    int  poff[5], sidx[5];
    bool pval[5];
#pragma unroll
    for (int k = 0; k < 5; k++) {
        int idx = tid + (k << 8);
        pval[k] = (idx < NPIX);
        int row = idx / EXC;
        int c   = idx - row * EXC;
        sidx[k] = row * SPS + c;
        int gy = min(oy0 + row, D - 1);
        int gx = min(ox0 + c,   D - 1);
        poff[k] = gy * D + gx;
    }

    // packed systolic z accumulators: Acc2[field][k] = (even-row, odd-row)
    // fields: 0=m1, 1=m2, 2=sq(a^2+b^2), 3=sab
    f2 Acc2[4][11] = {};
    float ssim_acc = 0.f, cs_acc = 0.f;

    const bool vx  = (ox0 + col < O);
    const bool vy0 = vx && (oy0 + 2 * yg < O);
    const bool vy1 = vx && (oy0 + 2 * yg + 1 < O);

    // preload first plane
    float2 Pld[5];
    {
        long zoff = (long)oz0 * D2;
#pragma unroll
        for (int k = 0; k < 5; k++)
            if (pval[k]) Pld[k] = make_float2(A[zoff + poff[k]], B[zoff + poff[k]]);
    }

    for (int it = 0; it < nplanes + 2; ++it) {
        // ---- C: y-conv + systolic for plane it-2 (reads TX4 from last iter's B)
        if (it >= 2) {
            f2 acc[4] = {};
#pragma unroll
            for (int j = 0; j < 12; j++) {
                float4 q = TX4[(2 * yg + j) * TPS + col];
                float we = (j < 11) ? P.g[j]     : 0.f;
                float wo = (j > 0)  ? P.g[j - 1] : 0.f;
                f2 w = mkf2(we, wo);
                acc[0] = PKFMA(w, mkf2(q.x, q.x), acc[0]);
                acc[1] = PKFMA(w, mkf2(q.y, q.y), acc[1]);
                acc[2] = PKFMA(w, mkf2(q.z, q.z), acc[2]);
                acc[3] = PKFMA(w, mkf2(q.w, q.w), acc[3]);
            }

            // packed systolic z-accumulate: A[k] = g[10-k]*s + A[k+1]
#pragma unroll
            for (int f = 0; f < 4; f++) {
                f2 s = acc[f];
#pragma unroll
                for (int k = 0; k < 10; k++) {
                    f2 w = mkf2(P.g[10 - k], P.g[10 - k]);
                    Acc2[f][k] = PKFMA(w, s, Acc2[f][k + 1]);
                }
                Acc2[f][10] = mkf2(P.g[0], P.g[0]) * s;
            }

            // completed output plane: Acc2[..][0] holds plane (it-2)-10 conv
            if (it >= 12) {
#pragma unroll
                for (int r = 0; r < 2; r++) {
                    bool valid = r ? vy1 : vy0;
                    if (!valid) continue;
                    float m1v = r ? Acc2[0][0].y : Acc2[0][0].x;
                    float m2v = r ? Acc2[1][0].y : Acc2[1][0].x;
                    float sqv = r ? Acc2[2][0].y : Acc2[2][0].x;
                    float sbv = r ? Acc2[3][0].y : Acc2[3][0].x;
                    float mu11 = m1v * m1v, mu22 = m2v * m2v, mu12 = m1v * m2v;
                    float sg12 = sbv - mu12;
                    float sgs  = sqv - mu11 - mu22;     // sigma1_sq + sigma2_sq
                    float v1 = 2.f * sg12 + C2;
                    float v2 = sgs + C2;
                    cs_acc   += v1 / v2;
                    ssim_acc += ((2.f * mu12 + C1) * v1) / ((mu11 + mu22 + C1) * v2);
                }
            }
        }

        // ---- A: stage plane `it` into S[it&1]; prefetch plane it+1.
        // (S[it&1] was last read by B at iter it-1, across >=1 barrier.)
        if (it < nplanes) {
            float2* Sc = S[it & 1];
#pragma unroll
            for (int k = 0; k < 5; k++)
                if (pval[k]) Sc[sidx[k]] = Pld[k];
            if (it + 1 < nplanes) {
                long zoff = (long)(oz0 + it + 1) * D2;
#pragma unroll
                for (int k = 0; k < 5; k++)
                    if (pval[k]) Pld[k] = make_float2(A[zoff + poff[k]], B[zoff + poff[k]]);
            }
        }

        __syncthreads();   // TX consumed by C -> B may overwrite

        // ---- B: x-conv plane it-1: S[(it-1)&1] -> TX4 (single buffer).
        // 168 tasks, each a run of 4 output cols in one ext row.
        if (it >= 1 && it <= nplanes && tid < EXR * 4) {
            const float2* Sc = S[(it - 1) & 1];
            const int row = tid >> 2;
            const int cg  = tid & 3;          // c0 = 4*cg
            const float4* srow = (const float4*)(Sc + row * SPS);
            f2 mm[4] = {}, qq[4] = {};
#pragma unroll
            for (int i = 0; i < 7; i++) {
                float4 qv = srow[2 * cg + i];
#pragma unroll
                for (int h = 0; h < 2; h++) {
                    const int jj = 2 * i + h;
                    float a = h ? qv.z : qv.x;
                    float b = h ? qv.w : qv.y;
                    f2 ab  = mkf2(a, b);
                    float e  = a * b;
                    float s2 = fmaf(a, a, b * b);
                    f2 se2 = mkf2(s2, e);
#pragma unroll
                    for (int cc = 0; cc < 4; cc++) {
                        const int j = jj - cc;
                        if (j >= 0 && j <= 10) {
                            f2 w = mkf2(P.g[j], P.g[j]);
                            mm[cc] = PKFMA(w, ab,  mm[cc]);
                            qq[cc] = PKFMA(w, se2, qq[cc]);
                        }
                    }
                }
            }
#pragma unroll
            for (int cc = 0; cc < 4; cc++)
                TX4[row * TPS + 4 * cg + cc] =
                    make_float4(mm[cc].x, mm[cc].y, qq[cc].x, qq[cc].y);
        }

        __syncthreads();   // TX ready for next C; S(it) visible for next B
    }

    // block reduce (reuse S's LDS; loop ended with a barrier so S is dead)
    float2* RED = (float2*)&S[0][0];
    RED[tid] = make_float2(ssim_acc, cs_acc);
    __syncthreads();
    for (int s = 128; s > 0; s >>= 1) {
        if (tid < s) {
            RED[tid].x += RED[tid + s].x;
            RED[tid].y += RED[tid + s].y;
        }
        __syncthreads();
    }
    if (tid == 0) {
        atomicAdd(&wsf[level],     RED[0].x);
        atomicAdd(&wsf[5 + level], RED[0].y);
        __threadfence();
        unsigned prev = atomicAdd((unsigned*)wsf + 20, 1u);
        if (prev == (unsigned)(P.blk0[5] - 1)) {
            // all blocks' sums are globally visible (their adds precede the
            // counter increment); read via device-scope RMW to dodge stale L2.
            double w[5];
            w[0] = (double)0.0448f; w[1] = (double)0.2856f; w[2] = (double)0.3001f;
            w[3] = (double)0.2363f; w[4] = (double)0.1333f;
            double prod = 1.0;
            for (int l = 0; l < 4; l++) {
                float cs = atomicAdd(&wsf[5 + l], 0.0f);
                prod *= pow((double)cs / P.cnt[l], w[l]);
            }
            float sm = atomicAdd(&wsf[4], 0.0f);
            prod *= pow((double)sm / P.cnt[4], w[4]);
            P.out[0] = (float)prod;
        }
    }
}

extern "C" void kernel_launch(void* const* d_in, const int* in_sizes, int n_in,
                              void* d_out, int out_size, void* d_ws, size_t ws_size,
                              hipStream_t stream) {
    (void)in_sizes; (void)n_in; (void)out_size; (void)ws_size;
    const float* img1 = (const float*)d_in[0];
    const float* img2 = (const float*)d_in[1];
    float* wsf = (float*)d_ws;
    float* out = (float*)d_out;

    const int Ds[5]  = {192, 96, 48, 24, 12};
    // fine-grain single-phase packing at 5 blocks/CU capacity (28.9KB LDS):
    // 1008 L0 + 144 L1 + 36 L2 + 2 L3 + 2 L4 = 1192 blocks (~4.66/CU),
    // uniform 36-plane slices.
    const int ZCs[5] = {26, 26, 14, 14, 2};

    // pyramid buffers in workspace
    float* bufA[5] = {nullptr};
    float* bufB[5] = {nullptr};
    size_t o = 32;
    for (int l = 1; l < 5; l++) {
        long n = 2L * Ds[l] * Ds[l] * Ds[l];
        bufA[l] = wsf + o; o += (size_t)n;
        bufB[l] = wsf + o; o += (size_t)n;
    }

    init_kernel<<<1, 64, 0, stream>>>(wsf);

    PyrParams PP;
    PP.src[0] = img1; PP.src[1] = img2;
    for (int l = 1; l < 5; l++) { PP.dst[0][l - 1] = bufA[l]; PP.dst[1][l - 1] = bufB[l]; }
    pyramid_kernel<<<216 * 2 * 2, 256, 0, stream>>>(PP, wsf);

    AllParams P;
    P.A[0] = img1; P.B[0] = img2;
    for (int l = 1; l < 5; l++) { P.A[l] = bufA[l]; P.B[l] = bufB[l]; }
    P.out = out;
    int acc = 0;
    for (int l = 0; l < 5; l++) {
        int D = Ds[l], O = D - 10, ZC = ZCs[l];
        int nTx = (O + TSX - 1) / TSX;
        int nTy = (O + TSY - 1) / TSY;
        int ZCn = (O + ZC - 1) / ZC;
        P.D[l] = D; P.O[l] = O; P.zc[l] = ZC; P.nTx[l] = nTx; P.nTy[l] = nTy;
        P.blk0[l] = acc;
        acc += nTx * nTy * 2 * ZCn;
        double Od = (double)O;
        P.cnt[l] = 2.0 * Od * Od * Od;
    }
    P.blk0[5] = acc;

    // gaussian taps (same float expression the device version used)
    {
        float s = 0.f;
        for (int i = 0; i < 11; i++) {
            float d = (float)(i - 5);
            P.g[i] = expf(-d * d / 4.5f);
            s += P.g[i];
        }
        for (int i = 0; i < 11; i++) P.g[i] /= s;
    }

    ssim_all_kernel<<<acc, 256, 0, stream>>>(P, wsf);
}

// Round 11
// 298.364 us; speedup vs baseline: 1.2369x; 1.1268x over previous
//
#include <hip/hip_runtime.h>
#include <math.h>

// ---------------------------------------------------------------------------
// MS-SSIM 3D (window 11, sigma 1.5, 5 levels) for (2,1,192,192,192) fp32 pairs.
//
// ws float layout:
//   [0..4]   ssim_sum[level]      (float atomics)
//   [5..9]   cs_sum[level]        (float atomics)
//   [10..14] min_enc[level]       (sortable-uint atomicMin)
//   [15..19] max_enc[level]       (sortable-uint atomicMax)
//   [20]     completion counter   (uint)
//   [32.. ]  pyramid images (levels 1..4, img1 then img2 per level)
//
// R15 = exact R10 (best measured: 299.6 us total, ssim 159.7 us).
// Session findings locked in:
//  - v_pk_fma_f32 packing of x/y/z conv loops (-22%, R10) + 4-field algebra
//    (a, b, a^2+b^2, ab) -- the only changes that ever paid.
//  - Single-barrier pipeline A|B|C in ONE interval (phase mixing matters:
//    splitting intervals cost 5-20% in R7/R14).
//  - ZCs{46,26,14,14,2}: 760 blocks, halo-amortized, single-phase.
//  - Structural variants all regressed: dbuf pipeline (R8), staging re-plumb
//    (R11), pyramid/ssim fusion (R13), TX-single+reorder (R14). Occupancy
//    is NOT the limiter (R14: flat at ~24% despite 5-blocks/CU capacity).
//  - ~140us of total is fixed harness overhead (R13 fusion proved it).
//  - Do NOT force waves_per_eu: spills Acc to scratch (R6, 80MB WRITE_SIZE).
// ---------------------------------------------------------------------------

typedef float f2 __attribute__((ext_vector_type(2)));
#define PKFMA(a, b, c) __builtin_elementwise_fma((a), (b), (c))

__device__ __forceinline__ f2 mkf2(float x, float y) { f2 r; r.x = x; r.y = y; return r; }

__device__ __forceinline__ unsigned enc_f(float f) {
    unsigned u = __float_as_uint(f);
    return (u & 0x80000000u) ? ~u : (u | 0x80000000u);
}
__device__ __forceinline__ float dec_f(unsigned e) {
    unsigned u = (e & 0x80000000u) ? (e ^ 0x80000000u) : ~e;
    return __uint_as_float(u);
}

__global__ void init_kernel(float* wsf) {
    unsigned* wsu = (unsigned*)wsf;
    int t = threadIdx.x;
    if (t < 10)       wsf[t] = 0.0f;
    else if (t < 15)  wsu[t] = 0xFFFFFFFFu;  // min slots
    else if (t < 20)  wsu[t] = 0u;           // max slots
    else if (t == 20) wsu[t] = 0u;           // completion counter
}

// ---------------------------------------------------------------------------
// Fused pyramid: each block owns a 32^3 region of level 0 for one (img,batch),
// produces 16^3 of L1 (regs), 8^3 of L2, 4^3 of L3, 2^3 of L4 via LDS, writes
// all levels to global, and block-reduces min/max per level (img1 only).
// ---------------------------------------------------------------------------
struct PyrParams {
    const float* src[2];   // img1, img2
    float* dst[2][4];      // [img][level-1]
};

__launch_bounds__(256, 4)
__global__ void pyramid_kernel(PyrParams P, float* wsf) {
    __shared__ float L1[16 * 256];   // 16^3
    __shared__ float L2[512];        // 8^3
    __shared__ float L3[64];         // 4^3
    __shared__ float smn[4], smx[4];
    unsigned* wsu = (unsigned*)wsf;

    const int tid = threadIdx.x;
    int blk = blockIdx.x;
    int r = blk % 216; blk /= 216;
    int batch = blk & 1;
    int im = blk >> 1;
    const int rx = r % 6, ry = (r / 6) % 6, rz = r / 36;

    const long N0 = 192L * 192 * 192;
    const float* src = P.src[im] + (long)batch * N0;
    float* d1 = P.dst[im][0] + (long)batch * 96 * 96 * 96;
    float* d2 = P.dst[im][1] + (long)batch * 48 * 48 * 48;
    float* d3 = P.dst[im][2] + (long)batch * 24 * 24 * 24;
    float* d4 = P.dst[im][3] + (long)batch * 12 * 12 * 12;

    const int tx = tid & 15, ty = tid >> 4;
    float mnv[5], mxv[5];
#pragma unroll
    for (int l = 0; l < 5; l++) { mnv[l] = INFINITY; mxv[l] = -INFINITY; }

    const long D = 192, D2 = 192L * 192;
    const int gx = 2 * (rx * 16 + tx);
    const int gy = 2 * (ry * 16 + ty);
#pragma unroll 4
    for (int z = 0; z < 16; z++) {
        const int gz = 2 * (rz * 16 + z);
        long base = (long)gz * D2 + (long)gy * D + gx;
        float2 a00 = *(const float2*)(src + base);
        float2 a01 = *(const float2*)(src + base + D);
        float2 a10 = *(const float2*)(src + base + D2);
        float2 a11 = *(const float2*)(src + base + D2 + D);
        float lo = fminf(fminf(fminf(a00.x, a00.y), fminf(a01.x, a01.y)),
                         fminf(fminf(a10.x, a10.y), fminf(a11.x, a11.y)));
        float hi = fmaxf(fmaxf(fmaxf(a00.x, a00.y), fmaxf(a01.x, a01.y)),
                         fmaxf(fmaxf(a10.x, a10.y), fmaxf(a11.x, a11.y)));
        mnv[0] = fminf(mnv[0], lo); mxv[0] = fmaxf(mxv[0], hi);
        float s = (a00.x + a00.y + a01.x + a01.y +
                   a10.x + a10.y + a11.x + a11.y) * 0.125f;
        mnv[1] = fminf(mnv[1], s); mxv[1] = fmaxf(mxv[1], s);
        d1[(long)(rz * 16 + z) * 96 * 96 + (ry * 16 + ty) * 96 + (rx * 16 + tx)] = s;
        L1[z * 256 + ty * 16 + tx] = s;
    }
    __syncthreads();

#pragma unroll
    for (int k = 0; k < 2; k++) {
        int o = tid + (k << 8);
        int x = o & 7, y = (o >> 3) & 7, z = o >> 6;
        float s = (L1[(2 * z) * 256 + (2 * y) * 16 + 2 * x] +
                   L1[(2 * z) * 256 + (2 * y) * 16 + 2 * x + 1] +
                   L1[(2 * z) * 256 + (2 * y + 1) * 16 + 2 * x] +
                   L1[(2 * z) * 256 + (2 * y + 1) * 16 + 2 * x + 1] +
                   L1[(2 * z + 1) * 256 + (2 * y) * 16 + 2 * x] +
                   L1[(2 * z + 1) * 256 + (2 * y) * 16 + 2 * x + 1] +
                   L1[(2 * z + 1) * 256 + (2 * y + 1) * 16 + 2 * x] +
                   L1[(2 * z + 1) * 256 + (2 * y + 1) * 16 + 2 * x + 1]) * 0.125f;
        mnv[2] = fminf(mnv[2], s); mxv[2] = fmaxf(mxv[2], s);
        d2[(long)(rz * 8 + z) * 48 * 48 + (ry * 8 + y) * 48 + (rx * 8 + x)] = s;
        L2[o] = s;
    }
    __syncthreads();

    if (tid < 64) {
        int x = tid & 3, y = (tid >> 2) & 3, z = tid >> 4;
        float s = (L2[(2 * z) * 64 + (2 * y) * 8 + 2 * x] +
                   L2[(2 * z) * 64 + (2 * y) * 8 + 2 * x + 1] +
                   L2[(2 * z) * 64 + (2 * y + 1) * 8 + 2 * x] +
                   L2[(2 * z) * 64 + (2 * y + 1) * 8 + 2 * x + 1] +
                   L2[(2 * z + 1) * 64 + (2 * y) * 8 + 2 * x] +
                   L2[(2 * z + 1) * 64 + (2 * y) * 8 + 2 * x + 1] +
                   L2[(2 * z + 1) * 64 + (2 * y + 1) * 8 + 2 * x] +
                   L2[(2 * z + 1) * 64 + (2 * y + 1) * 8 + 2 * x + 1]) * 0.125f;
        mnv[3] = fminf(mnv[3], s); mxv[3] = fmaxf(mxv[3], s);
        d3[(long)(rz * 4 + z) * 24 * 24 + (ry * 4 + y) * 24 + (rx * 4 + x)] = s;
        L3[tid] = s;
    }
    __syncthreads();

    if (tid < 8) {
        int x = tid & 1, y = (tid >> 1) & 1, z = tid >> 2;
        float s = (L3[(2 * z) * 16 + (2 * y) * 4 + 2 * x] +
                   L3[(2 * z) * 16 + (2 * y) * 4 + 2 * x + 1] +
                   L3[(2 * z) * 16 + (2 * y + 1) * 4 + 2 * x] +
                   L3[(2 * z) * 16 + (2 * y + 1) * 4 + 2 * x + 1] +
                   L3[(2 * z + 1) * 16 + (2 * y) * 4 + 2 * x] +
                   L3[(2 * z + 1) * 16 + (2 * y) * 4 + 2 * x + 1] +
                   L3[(2 * z + 1) * 16 + (2 * y + 1) * 4 + 2 * x] +
                   L3[(2 * z + 1) * 16 + (2 * y + 1) * 4 + 2 * x + 1]) * 0.125f;
        mnv[4] = fminf(mnv[4], s); mxv[4] = fmaxf(mxv[4], s);
        d4[(long)(rz * 2 + z) * 12 * 12 + (ry * 2 + y) * 12 + (rx * 2 + x)] = s;
    }

    const int lane = tid & 63, w = tid >> 6;
#pragma unroll
    for (int l = 0; l < 5; l++) {
        float mn = mnv[l], mx = mxv[l];
        for (int o = 32; o; o >>= 1) {
            mn = fminf(mn, __shfl_down(mn, o));
            mx = fmaxf(mx, __shfl_down(mx, o));
        }
        __syncthreads();
        if (lane == 0) { smn[w] = mn; smx[w] = mx; }
        __syncthreads();
        if (tid == 0 && im == 0) {
            for (int i = 1; i < 4; i++) { mn = fminf(mn, smn[i]); mx = fmaxf(mx, smx[i]); }
            atomicMin(&wsu[10 + l], enc_f(mn));
            atomicMax(&wsu[15 + l], enc_f(mx));
        }
    }
}

// ---------------------------------------------------------------------------
// Combined SSIM kernel: one dispatch, all 5 levels + fused final reduction.
// 16(x) x 32(y) output tile; thread owns (col, 2 rows). Single-barrier
// pipeline: iter i stages S(i), x-convs plane i-1, y-convs plane i-2.
// Hot loops use packed fp32 (v_pk_fma_f32 via float2 ext_vector fma).
// ---------------------------------------------------------------------------
#define TSX 16
#define TSY 32
#define EXR 42            // ext rows (32+10)
#define EXC 26            // ext cols (16+10)
#define SPS 26            // S row stride in float2 (exact 13 float4, odd)
#define NPIX (EXR * EXC)  // 1092
#define TPS 17            // TX row stride in float4

struct AllParams {
    const float* A[5];
    const float* B[5];
    float* out;
    double cnt[5];
    int D[5], O[5], zc[5], nTx[5], nTy[5];
    int blk0[6];          // cumulative block offsets, level order 0..4
    float g[11];          // gaussian taps (uniform -> SGPRs)
};

// No waves_per_eu attr (R6 lesson: forcing occupancy spills Acc to scratch).
__launch_bounds__(256)
__global__ void ssim_all_kernel(AllParams P, float* wsf) {
    __shared__ __align__(16) float2 S[2][EXR * SPS];    // 2 x 8736 B
    __shared__ __align__(16) float4 TX4[2][EXR * TPS];  // 2 x 11424 B
    // total 40320 B

    const int tid = threadIdx.x;
    const int col = tid & 15;
    const int yg  = tid >> 4;      // 0..15, owns output rows 2yg, 2yg+1

    // ---- decode level + tile from flat blockIdx.x
    int level = 0;
    {
        int b = blockIdx.x;
#pragma unroll
        for (int l = 1; l < 5; l++)
            if (b >= P.blk0[l]) level = l;
    }
    int rel = blockIdx.x - P.blk0[level];
    const int D   = P.D[level];
    const int O   = P.O[level];
    const int ZC  = P.zc[level];
    const int nTx = P.nTx[level];
    const int nTy = P.nTy[level];

    const int tx = rel % nTx;  rel /= nTx;
    const int ty = rel % nTy;  rel /= nTy;
    const int batch = rel & 1;
    const int chunk = rel >> 1;

    const int oz0 = chunk * ZC;
    const int oz1 = min(oz0 + ZC, O);
    const int nplanes = oz1 - oz0 + 10;
    const int ox0 = tx * TSX;
    const int oy0 = ty * TSY;
    const int D2  = D * D;
    const float* A = P.A[level] + (long)batch * D * D2;
    const float* B = P.B[level] + (long)batch * D * D2;

    // C1/C2 from this level's img1 min/max (computed by pyramid kernel)
    const unsigned* wsu = (const unsigned*)wsf;
    float mxv = dec_f(wsu[15 + level]);
    float mnv = dec_f(wsu[10 + level]);
    float maxval = (mxv > 128.f) ? 255.f : 1.f;
    float minval = (mnv < -0.5f) ? -1.f : 0.f;
    float Lr = maxval - minval;
    float C1 = 0.01f * Lr; C1 *= C1;
    float C2 = 0.03f * Lr; C2 *= C2;

    // per-thread staging slots (plane-invariant offsets); 1092 = 42*26
    int  poff[5], sidx[5];
    bool pval[5];
#pragma unroll
    for (int k = 0; k < 5; k++) {
        int idx = tid + (k << 8);
        pval[k] = (idx < NPIX);
        int row = idx / EXC;
        int c   = idx - row * EXC;
        sidx[k] = row * SPS + c;
        int gy = min(oy0 + row, D - 1);
        int gx = min(ox0 + c,   D - 1);
        poff[k] = gy * D + gx;
    }

    // packed systolic z accumulators: Acc2[field][k] = (even-row, odd-row)
    // fields: 0=m1, 1=m2, 2=sq(a^2+b^2), 3=sab
    f2 Acc2[4][11] = {};
    float ssim_acc = 0.f, cs_acc = 0.f;

    const bool vx  = (ox0 + col < O);
    const bool vy0 = vx && (oy0 + 2 * yg < O);
    const bool vy1 = vx && (oy0 + 2 * yg + 1 < O);

    // preload first plane
    float2 Pld[5];
    {
        long zoff = (long)oz0 * D2;
#pragma unroll
        for (int k = 0; k < 5; k++)
            if (pval[k]) Pld[k] = make_float2(A[zoff + poff[k]], B[zoff + poff[k]]);
    }

    // Pipeline: iter it: stage S(it) | x-conv plane it-1 | y-conv plane it-2.
    // One barrier/iter; all producer->consumer and WAR pairs cross >=1 barrier.
    for (int it = 0; it < nplanes + 2; ++it) {
        // ---- A: stage plane `it` into S[it&1]; prefetch plane it+1
        if (it < nplanes) {
            float2* Sc = S[it & 1];
#pragma unroll
            for (int k = 0; k < 5; k++)
                if (pval[k]) Sc[sidx[k]] = Pld[k];
            if (it + 1 < nplanes) {
                long zoff = (long)(oz0 + it + 1) * D2;
#pragma unroll
                for (int k = 0; k < 5; k++)
                    if (pval[k]) Pld[k] = make_float2(A[zoff + poff[k]], B[zoff + poff[k]]);
            }
        }

        // ---- B: x-conv plane it-1: S[(it-1)&1] -> TX4[(it-1)&1]
        // 168 tasks, each a run of 4 output cols in one ext row.
        // Packed: (m1,m2) and (sq,sab) pairs -> 2 pk_fma per tap per col.
        if (it >= 1 && it <= nplanes && tid < EXR * 4) {
            const float2* Sc = S[(it - 1) & 1];
            float4* Tc = TX4[(it - 1) & 1];
            const int row = tid >> 2;
            const int cg  = tid & 3;          // c0 = 4*cg
            const float4* srow = (const float4*)(Sc + row * SPS);
            f2 mm[4] = {}, qq[4] = {};
#pragma unroll
            for (int i = 0; i < 7; i++) {
                float4 qv = srow[2 * cg + i];
#pragma unroll
                for (int h = 0; h < 2; h++) {
                    const int jj = 2 * i + h;
                    float a = h ? qv.z : qv.x;
                    float b = h ? qv.w : qv.y;
                    f2 ab  = mkf2(a, b);
                    float e  = a * b;
                    float s2 = fmaf(a, a, b * b);
                    f2 se2 = mkf2(s2, e);
#pragma unroll
                    for (int cc = 0; cc < 4; cc++) {
                        const int j = jj - cc;
                        if (j >= 0 && j <= 10) {
                            f2 w = mkf2(P.g[j], P.g[j]);
                            mm[cc] = PKFMA(w, ab,  mm[cc]);
                            qq[cc] = PKFMA(w, se2, qq[cc]);
                        }
                    }
                }
            }
#pragma unroll
            for (int cc = 0; cc < 4; cc++)
                Tc[row * TPS + 4 * cg + cc] =
                    make_float4(mm[cc].x, mm[cc].y, qq[cc].x, qq[cc].y);
        }

        // ---- C: y-conv + systolic for plane it-2 (reads TX4[(it-2)&1 == it&1])
        // Packed: (se,so) pairs -> 4 pk_fma per row read.
        if (it >= 2) {
            const float4* Tc = TX4[it & 1];
            f2 acc[4] = {};
#pragma unroll
            for (int j = 0; j < 12; j++) {
                float4 q = Tc[(2 * yg + j) * TPS + col];
                float we = (j < 11) ? P.g[j]     : 0.f;
                float wo = (j > 0)  ? P.g[j - 1] : 0.f;
                f2 w = mkf2(we, wo);
                acc[0] = PKFMA(w, mkf2(q.x, q.x), acc[0]);
                acc[1] = PKFMA(w, mkf2(q.y, q.y), acc[1]);
                acc[2] = PKFMA(w, mkf2(q.z, q.z), acc[2]);
                acc[3] = PKFMA(w, mkf2(q.w, q.w), acc[3]);
            }

            // packed systolic z-accumulate: A[k] = g[10-k]*s + A[k+1]
#pragma unroll
            for (int f = 0; f < 4; f++) {
                f2 s = acc[f];
#pragma unroll
                for (int k = 0; k < 10; k++) {
                    f2 w = mkf2(P.g[10 - k], P.g[10 - k]);
                    Acc2[f][k] = PKFMA(w, s, Acc2[f][k + 1]);
                }
                Acc2[f][10] = mkf2(P.g[0], P.g[0]) * s;
            }

            // completed output plane: Acc2[..][0] holds plane (it-2)-10 conv
            if (it >= 12) {
#pragma unroll
                for (int r = 0; r < 2; r++) {
                    bool valid = r ? vy1 : vy0;
                    if (!valid) continue;
                    float m1v = r ? Acc2[0][0].y : Acc2[0][0].x;
                    float m2v = r ? Acc2[1][0].y : Acc2[1][0].x;
                    float sqv = r ? Acc2[2][0].y : Acc2[2][0].x;
                    float sbv = r ? Acc2[3][0].y : Acc2[3][0].x;
                    float mu11 = m1v * m1v, mu22 = m2v * m2v, mu12 = m1v * m2v;
                    float sg12 = sbv - mu12;
                    float sgs  = sqv - mu11 - mu22;     // sigma1_sq + sigma2_sq
                    float v1 = 2.f * sg12 + C2;
                    float v2 = sgs + C2;
                    cs_acc   += v1 / v2;
                    ssim_acc += ((2.f * mu12 + C1) * v1) / ((mu11 + mu22 + C1) * v2);
                }
            }
        }

        __syncthreads();
    }

    // block reduce (reuse S's LDS; loop ended with a barrier so S is dead)
    float2* RED = (float2*)&S[0][0];
    RED[tid] = make_float2(ssim_acc, cs_acc);
    __syncthreads();
    for (int s = 128; s > 0; s >>= 1) {
        if (tid < s) {
            RED[tid].x += RED[tid + s].x;
            RED[tid].y += RED[tid + s].y;
        }
        __syncthreads();
    }
    if (tid == 0) {
        atomicAdd(&wsf[level],     RED[0].x);
        atomicAdd(&wsf[5 + level], RED[0].y);
        __threadfence();
        unsigned prev = atomicAdd((unsigned*)wsf + 20, 1u);
        if (prev == (unsigned)(P.blk0[5] - 1)) {
            // all blocks' sums are globally visible (their adds precede the
            // counter increment); read via device-scope RMW to dodge stale L2.
            double w[5];
            w[0] = (double)0.0448f; w[1] = (double)0.2856f; w[2] = (double)0.3001f;
            w[3] = (double)0.2363f; w[4] = (double)0.1333f;
            double prod = 1.0;
            for (int l = 0; l < 4; l++) {
                float cs = atomicAdd(&wsf[5 + l], 0.0f);
                prod *= pow((double)cs / P.cnt[l], w[l]);
            }
            float sm = atomicAdd(&wsf[4], 0.0f);
            prod *= pow((double)sm / P.cnt[4], w[4]);
            P.out[0] = (float)prod;
        }
    }
}

extern "C" void kernel_launch(void* const* d_in, const int* in_sizes, int n_in,
                              void* d_out, int out_size, void* d_ws, size_t ws_size,
                              hipStream_t stream) {
    (void)in_sizes; (void)n_in; (void)out_size; (void)ws_size;
    const float* img1 = (const float*)d_in[0];
    const float* img2 = (const float*)d_in[1];
    float* wsf = (float*)d_ws;
    float* out = (float*)d_out;

    const int Ds[5]  = {192, 96, 48, 24, 12};
    // single-phase packing: 576 L0 + 144 L1 + 36 L2 + 2 L3 + 2 L4 = 760
    // blocks ~= 3/CU -- all co-resident, no tail.
    const int ZCs[5] = {46, 26, 14, 14, 2};

    // pyramid buffers in workspace
    float* bufA[5] = {nullptr};
    float* bufB[5] = {nullptr};
    size_t o = 32;
    for (int l = 1; l < 5; l++) {
        long n = 2L * Ds[l] * Ds[l] * Ds[l];
        bufA[l] = wsf + o; o += (size_t)n;
        bufB[l] = wsf + o; o += (size_t)n;
    }

    init_kernel<<<1, 64, 0, stream>>>(wsf);

    PyrParams PP;
    PP.src[0] = img1; PP.src[1] = img2;
    for (int l = 1; l < 5; l++) { PP.dst[0][l - 1] = bufA[l]; PP.dst[1][l - 1] = bufB[l]; }
    pyramid_kernel<<<216 * 2 * 2, 256, 0, stream>>>(PP, wsf);

    AllParams P;
    P.A[0] = img1; P.B[0] = img2;
    for (int l = 1; l < 5; l++) { P.A[l] = bufA[l]; P.B[l] = bufB[l]; }
    P.out = out;
    int acc = 0;
    for (int l = 0; l < 5; l++) {
        int D = Ds[l], O = D - 10, ZC = ZCs[l];
        int nTx = (O + TSX - 1) / TSX;
        int nTy = (O + TSY - 1) / TSY;
        int ZCn = (O + ZC - 1) / ZC;
        P.D[l] = D; P.O[l] = O; P.zc[l] = ZC; P.nTx[l] = nTx; P.nTy[l] = nTy;
        P.blk0[l] = acc;
        acc += nTx * nTy * 2 * ZCn;
        double Od = (double)O;
        P.cnt[l] = 2.0 * Od * Od * Od;
    }
    P.blk0[5] = acc;

    // gaussian taps (same float expression the device version used)
    {
        float s = 0.f;
        for (int i = 0; i < 11; i++) {
            float d = (float)(i - 5);
            P.g[i] = expf(-d * d / 4.5f);
            s += P.g[i];
        }
        for (int i = 0; i < 11; i++) P.g[i] /= s;
    }

    ssim_all_kernel<<<acc, 256, 0, stream>>>(P, wsf);
}